// Round 4
// baseline (148.248 us; speedup 1.0000x reference)
//
#include <hip/hip_runtime.h>

// Head: B=4, T=4096, C=1024, H=64. out = softmax(causal((x@Wq+bq)@(x@Wk+bk)^T * C^-0.5)) @ (x@Wv+bv)
#define B_ 4
#define T_ 4096
#define C_ 1024
#define H_ 64
// C^-0.5 * log2(e): folds softmax scale into Q, moves softmax into exp2 domain.
#define QSCALE 0.045084220027780106f

typedef float  f32x4  __attribute__((ext_vector_type(4)));
typedef __bf16 bf16x8 __attribute__((ext_vector_type(8)));
typedef __bf16 bf16x4 __attribute__((ext_vector_type(4)));

#define MFMA16(a, b, c) __builtin_amdgcn_mfma_f32_16x16x32_bf16((a), (b), (c), 0, 0, 0)

// ---------------------------------------------------------------------------
// prep: Wt[mat][n][k] = W_mat[k][n] as bf16 (LDS tile transpose). 192 blocks.
// ---------------------------------------------------------------------------
__global__ __launch_bounds__(256) void prep_wt(const float* __restrict__ Wk,
                                               const float* __restrict__ Wq,
                                               const float* __restrict__ Wv,
                                               __bf16* __restrict__ Wt) {
    __shared__ float tile[16][65];
    int tid = threadIdx.x;
    int mat = blockIdx.x >> 6;
    int k0  = (blockIdx.x & 63) * 16;
    const float* W = (mat == 0) ? Wk : ((mat == 1) ? Wq : Wv);
#pragma unroll
    for (int i = 0; i < 4; ++i) {
        int e = i * 256 + tid;
        int ki = e >> 6, n = e & 63;
        tile[ki][n] = W[(size_t)(k0 + ki) * 64 + n];
    }
    __syncthreads();
#pragma unroll
    for (int i = 0; i < 4; ++i) {
        int e = i * 256 + tid;
        int n = e >> 4, kj = e & 15;
        Wt[(size_t)mat * 65536 + (size_t)n * 1024 + k0 + kj] = (__bf16)tile[kj][n];
    }
}

// ---------------------------------------------------------------------------
// proj: 1024 blocks x 4 waves, block = 16 rows, wave w = output cols
// [16w,16w+16) of K,Q,V. Depth-4 register pipeline: ~20 loads in flight per
// wave so L2/HBM latency is covered by MLP x TLP (16 waves/CU).
// ---------------------------------------------------------------------------
#define PLOAD(kk, X0, X1, W0, W1, W2) do {                                  \
    const float*  xp_ = xrow  + (kk) + g * 8;                               \
    const __bf16* wp_ = wbase + (kk) + g * 8;                               \
    X0 = *(const f32x4*)(xp_);                                              \
    X1 = *(const f32x4*)(xp_ + 4);                                          \
    W0 = *(const bf16x8*)(wp_);                                             \
    W1 = *(const bf16x8*)(wp_ + 65536);                                     \
    W2 = *(const bf16x8*)(wp_ + 131072);                                    \
} while (0)

#define PCONS(X0, X1, W0, W1, W2) do {                                      \
    bf16x8 av_;                                                             \
    av_[0] = (__bf16)X0[0]; av_[1] = (__bf16)X0[1];                         \
    av_[2] = (__bf16)X0[2]; av_[3] = (__bf16)X0[3];                         \
    av_[4] = (__bf16)X1[0]; av_[5] = (__bf16)X1[1];                         \
    av_[6] = (__bf16)X1[2]; av_[7] = (__bf16)X1[3];                         \
    acc0 = MFMA16(av_, W0, acc0);                                           \
    acc1 = MFMA16(av_, W1, acc1);                                           \
    acc2 = MFMA16(av_, W2, acc2);                                           \
} while (0)

__global__ __launch_bounds__(256) void proj_qkv(const float* __restrict__ x,
                                                const __bf16* __restrict__ Wt,
                                                const float* __restrict__ bk,
                                                const float* __restrict__ bq,
                                                const float* __restrict__ bv,
                                                __bf16* __restrict__ Kg,
                                                __bf16* __restrict__ Qg,
                                                __bf16* __restrict__ Vt) {
    int tid  = threadIdx.x;
    int w    = tid >> 6;
    int lane = tid & 63;
    int lo = lane & 15, g = lane >> 4;

    int row0 = blockIdx.x * 16;
    const float*  xrow  = x  + (size_t)(row0 + lo) * C_;
    const __bf16* wbase = Wt + (size_t)(w * 16 + lo) * C_;

    f32x4 acc0 = (f32x4){0.f, 0.f, 0.f, 0.f};
    f32x4 acc1 = (f32x4){0.f, 0.f, 0.f, 0.f};
    f32x4 acc2 = (f32x4){0.f, 0.f, 0.f, 0.f};

    f32x4  xA0, xA1, xB0, xB1, xC0, xC1, xD0, xD1;
    bf16x8 wA0, wA1, wA2, wB0, wB1, wB2, wC0, wC1, wC2, wD0, wD1, wD2;

    PLOAD(0,  xA0, xA1, wA0, wA1, wA2);
    PLOAD(32, xB0, xB1, wB0, wB1, wB2);
    PLOAD(64, xC0, xC1, wC0, wC1, wC2);
    PLOAD(96, xD0, xD1, wD0, wD1, wD2);

#pragma unroll 1
    for (int kk = 0; kk < C_ - 128; kk += 128) {
        PCONS(xA0, xA1, wA0, wA1, wA2);
        PLOAD(kk + 128, xA0, xA1, wA0, wA1, wA2);
        PCONS(xB0, xB1, wB0, wB1, wB2);
        PLOAD(kk + 160, xB0, xB1, wB0, wB1, wB2);
        PCONS(xC0, xC1, wC0, wC1, wC2);
        PLOAD(kk + 192, xC0, xC1, wC0, wC1, wC2);
        PCONS(xD0, xD1, wD0, wD1, wD2);
        PLOAD(kk + 224, xD0, xD1, wD0, wD1, wD2);
    }
    PCONS(xA0, xA1, wA0, wA1, wA2);
    PCONS(xB0, xB1, wB0, wB1, wB2);
    PCONS(xC0, xC1, wC0, wC1, wC2);
    PCONS(xD0, xD1, wD0, wD1, wD2);

    // epilogue. C/D layout: col = lo (h sub), row = 4g + r.
    int h = w * 16 + lo;
    float bks = bk[h], bqs = bq[h], bvs = bv[h];
    int b_   = row0 >> 12;
    int tloc = row0 & (T_ - 1);
#pragma unroll
    for (int r = 0; r < 4; ++r) {
        Kg[(size_t)(row0 + 4 * g + r) * H_ + h] = (__bf16)(acc0[r] + bks);
        Qg[(size_t)(row0 + 4 * g + r) * H_ + h] = (__bf16)((acc1[r] + bqs) * QSCALE);
    }
    bf16x4 pv;
#pragma unroll
    for (int r = 0; r < 4; ++r) pv[r] = (__bf16)(acc2[r] + bvs);
    *(bf16x4*)(Vt + (size_t)(b_ * 64 + h) * T_ + tloc + 4 * g) = pv;
}

// ---------------------------------------------------------------------------
// attn: flash attention, 8 waves/block, in-block split-k (R2 structure:
// 32 waves/CU, no inner barriers, direct-L2 K/V) + defer-max (T13).
// Swapped QK^T: St[k][q] = mfma(K, Q) so softmax rows are lane-local.
// ---------------------------------------------------------------------------
__global__ __launch_bounds__(512) void attn_fwd(const __bf16* __restrict__ Qg,
                                                const __bf16* __restrict__ Kg,
                                                const __bf16* __restrict__ Vt,
                                                float* __restrict__ out) {
    // 8 x 4KB regions: per-wave P-relayout buffer during the loop (first 2KB),
    // then the wave's 16x64 f32 acc partial. + ml[8][16][2].
    __shared__ alignas(16) char smem[8 * 4096 + 8 * 16 * 2 * 4];

    int tid  = threadIdx.x;
    int w    = tid >> 6;
    int lane = tid & 63;
    int lo = lane & 15, g = lane >> 4;

    int bid = blockIdx.x;
    int b   = bid & 3;
    int qt  = 255 - (bid >> 2);                    // heavy tiles launch first
    int q0  = qt * 16;

    char* pl = smem + w * 4096;                    // wave-private P buffer

    // Q as B-fragment: lane holds Q[q0+lo][c*32 + g*8 + j]  (already *QSCALE)
    const __bf16* qp = Qg + (size_t)(b * T_ + q0 + lo) * H_ + g * 8;
    bf16x8 qb0 = *(const bf16x8*)(qp);
    bf16x8 qb1 = *(const bf16x8*)(qp + 32);

    f32x4 acc[4];
#pragma unroll
    for (int ht = 0; ht < 4; ++ht) acc[ht] = (f32x4){0.f, 0.f, 0.f, 0.f};
    float m = -1e30f, l = 0.f;

    int niter = (q0 >> 6) + 1;                     // only last k-block is partial
    for (int kb = w; kb < niter; kb += 8) {
        int k0 = kb << 6;
        f32x4 st[4];
#pragma unroll
        for (int kt = 0; kt < 4; ++kt) {
            const __bf16* kp = Kg + (size_t)(b * T_ + k0 + kt * 16 + lo) * H_ + g * 8;
            bf16x8 ka0 = *(const bf16x8*)(kp);
            bf16x8 ka1 = *(const bf16x8*)(kp + 32);
            f32x4 z = (f32x4){0.f, 0.f, 0.f, 0.f};
            z = MFMA16(ka0, qb0, z);               // St[k][q]: col=q=lo, row=k=4g+r
            z = MFMA16(ka1, qb1, z);
            st[kt] = z;
        }
        if (kb == niter - 1) {                     // causal mask (partial tile)
#pragma unroll
            for (int kt = 0; kt < 4; ++kt)
#pragma unroll
                for (int r = 0; r < 4; ++r) {
                    int kabs = k0 + kt * 16 + 4 * g + r;
                    if (kabs > q0 + lo) st[kt][r] = -1e30f;
                }
        }
        // online softmax (exp2 domain) with defer-max: only rescale when some
        // row's max grew by > 11.5 (values then bounded by 2^11.5, safe).
        float mloc = -1e30f;
#pragma unroll
        for (int kt = 0; kt < 4; ++kt)
#pragma unroll
            for (int r = 0; r < 4; ++r) mloc = fmaxf(mloc, st[kt][r]);
        mloc = fmaxf(mloc, __shfl_xor(mloc, 16));
        mloc = fmaxf(mloc, __shfl_xor(mloc, 32));
        if (__any(mloc > m + 11.5f)) {
            float mnew  = fmaxf(m, mloc);
            float alpha = exp2f(m - mnew);
            l *= alpha;
            m = mnew;
#pragma unroll
            for (int r = 0; r < 4; ++r) {
                float ar = __shfl(alpha, 4 * g + r);
#pragma unroll
                for (int ht = 0; ht < 4; ++ht) acc[ht][r] *= ar;
            }
        }
        float ls = 0.f;
#pragma unroll
        for (int kt = 0; kt < 4; ++kt)
#pragma unroll
            for (int r = 0; r < 4; ++r) {
                float pe = exp2f(st[kt][r] - m);
                st[kt][r] = pe;
                ls += pe;
            }
        ls += __shfl_xor(ls, 16);
        ls += __shfl_xor(ls, 32);
        l += ls;
        // P -> LDS (bf16, XOR swizzle: 2-way max)
#pragma unroll
        for (int kt = 0; kt < 4; ++kt) {
            bf16x4 pk;
#pragma unroll
            for (int r = 0; r < 4; ++r) pk[r] = (__bf16)st[kt][r];
            int waddr = (lo * 128 + kt * 32 + g * 8) ^ ((lo & 7) << 4);
            *(bf16x4*)(pl + waddr) = pk;
        }
        // PV: A = P[q][k], B = V^T rows (16B/lane contiguous)
#pragma unroll
        for (int c = 0; c < 2; ++c) {
            int raddr = (lo * 128 + c * 64 + g * 16) ^ ((lo & 7) << 4);
            bf16x8 pa = *(const bf16x8*)(pl + raddr);
#pragma unroll
            for (int ht = 0; ht < 4; ++ht) {
                bf16x8 vb = *(const bf16x8*)(Vt + (size_t)(b * 64 + ht * 16 + lo) * T_ + k0 + c * 32 + g * 8);
                acc[ht] = MFMA16(pa, vb, acc[ht]);
            }
        }
    }

    // ---- write per-wave partials (reuses the P region; wave-private) ----
    float* ab = (float*)(smem + w * 4096);         // [16][64]
#pragma unroll
    for (int ht = 0; ht < 4; ++ht)
#pragma unroll
        for (int r = 0; r < 4; ++r)
            ab[(4 * g + r) * 64 + ht * 16 + lo] = acc[ht][r];
    float* ml = (float*)(smem + 8 * 4096);         // [8][16][2]
    if (g == 0) {
        ml[(w * 16 + lo) * 2 + 0] = m;
        ml[(w * 16 + lo) * 2 + 1] = l;
    }
    __syncthreads();

    // ---- merge 8 partials: 1024 outputs, 512 threads -> 2 each ----
    const float* fl = (const float*)smem;
#pragma unroll
    for (int i = 0; i < 2; ++i) {
        int e = i * 512 + tid;
        int q = e >> 6, h = e & 63;
        float M = -1e30f;
#pragma unroll
        for (int ww = 0; ww < 8; ++ww) M = fmaxf(M, ml[(ww * 16 + q) * 2]);
        float L = 0.f, O = 0.f;
#pragma unroll
        for (int ww = 0; ww < 8; ++ww) {
            float sc = exp2f(ml[(ww * 16 + q) * 2] - M);
            L += ml[(ww * 16 + q) * 2 + 1] * sc;
            O += fl[ww * 1024 + q * 64 + h] * sc;
        }
        out[(size_t)(b * T_ + q0 + q) * H_ + h] = O / L;
    }
}

// ---------------------------------------------------------------------------
extern "C" void kernel_launch(void* const* d_in, const int* in_sizes, int n_in,
                              void* d_out, int out_size, void* d_ws, size_t ws_size,
                              hipStream_t stream) {
    const float* x  = (const float*)d_in[0];
    const float* Wk = (const float*)d_in[1];
    const float* bk = (const float*)d_in[2];
    const float* Wq = (const float*)d_in[3];
    const float* bq = (const float*)d_in[4];
    const float* Wv = (const float*)d_in[5];
    const float* bv = (const float*)d_in[6];

    char* ws = (char*)d_ws;
    // ws layout: Wt 384KB | Kg 2MB | Qg 2MB | Vt 2MB
    __bf16* Wt = (__bf16*)(ws);
    __bf16* Kg = (__bf16*)(ws + 393216);
    __bf16* Qg = (__bf16*)(ws + 393216 + 2097152);
    __bf16* Vt = (__bf16*)(ws + 393216 + 2 * 2097152);
    float* out = (float*)d_out;

    prep_wt<<<192, 256, 0, stream>>>(Wk, Wq, Wv, Wt);
    proj_qkv<<<1024, 256, 0, stream>>>(x, Wt, bk, bq, bv, Kg, Qg, Vt);
    attn_fwd<<<B_ * (T_ / 16), 512, 0, stream>>>(Qg, Kg, Vt, out);
}

// Round 5
// 118.186 us; speedup vs baseline: 1.2544x; 1.2544x over previous
//
#include <hip/hip_runtime.h>

// Head: B=4, T=4096, C=1024, H=64. out = softmax(causal((x@Wq+bq)@(x@Wk+bk)^T * C^-0.5)) @ (x@Wv+bv)
#define B_ 4
#define T_ 4096
#define C_ 1024
#define H_ 64
// C^-0.5 * log2(e): folds softmax scale into Q, moves softmax into exp2 domain.
#define QSCALE 0.045084220027780106f

typedef float  f32x4  __attribute__((ext_vector_type(4)));
typedef __bf16 bf16x8 __attribute__((ext_vector_type(8)));
typedef __bf16 bf16x4 __attribute__((ext_vector_type(4)));

#define MFMA16(a, b, c) __builtin_amdgcn_mfma_f32_16x16x32_bf16((a), (b), (c), 0, 0, 0)

// async global->LDS, 16B per lane; LDS dest is wave-uniform base + lane*16.
__device__ __forceinline__ void gl16(const void* g, void* l) {
    __builtin_amdgcn_global_load_lds(
        (const __attribute__((address_space(1))) void*)g,
        (__attribute__((address_space(3))) void*)l, 16, 0, 0);
}

// ---------------------------------------------------------------------------
// prep: Wt[mat][n][k] = W_mat[k][n] as bf16 (LDS tile transpose). 192 blocks.
// ---------------------------------------------------------------------------
__global__ __launch_bounds__(256) void prep_wt(const float* __restrict__ Wk,
                                               const float* __restrict__ Wq,
                                               const float* __restrict__ Wv,
                                               __bf16* __restrict__ Wt) {
    __shared__ float tile[16][65];
    int tid = threadIdx.x;
    int mat = blockIdx.x >> 6;
    int k0  = (blockIdx.x & 63) * 16;
    const float* W = (mat == 0) ? Wk : ((mat == 1) ? Wq : Wv);
#pragma unroll
    for (int i = 0; i < 4; ++i) {
        int e = i * 256 + tid;
        int ki = e >> 6, n = e & 63;
        tile[ki][n] = W[(size_t)(k0 + ki) * 64 + n];
    }
    __syncthreads();
#pragma unroll
    for (int i = 0; i < 4; ++i) {
        int e = i * 256 + tid;
        int n = e >> 4, kj = e & 15;
        Wt[(size_t)mat * 65536 + (size_t)n * 1024 + k0 + kj] = (__bf16)tile[kj][n];
    }
}

// ---------------------------------------------------------------------------
// proj: m97-style LDS-staged GEMM. M=16384, N=192 (K|Q|V), K=1024.
// 512 blocks x 4 waves. BM=32, BN=192, BK=64. Double-buffered LDS staged via
// global_load_lds (linear dest, XOR-preswizzled global source; matching XOR
// on ds_read -> conflict-free). One barrier per K-step.
// Wave (w2=w>>1, wc=w&1): rows [w2*16,+16), cols [wc*96,+96) (6 n-tiles).
// ---------------------------------------------------------------------------
#define STAGE(xd, wd, kk) do {                                              \
    const char* xs_ = xsrc + (size_t)(kk) * 4;                              \
    gl16(xs_,          (xd) + wq * 1024);                                   \
    gl16(xs_ + 65536,  (xd) + 4096 + wq * 1024);                            \
    const char* ws_ = wsrc + (size_t)(kk) * 2;                              \
    gl16(ws_,           (wd) + wq * 1024);                                  \
    gl16(ws_ + 65536,   (wd) + 4096  + wq * 1024);                          \
    gl16(ws_ + 131072,  (wd) + 8192  + wq * 1024);                          \
    gl16(ws_ + 196608,  (wd) + 12288 + wq * 1024);                          \
    gl16(ws_ + 262144,  (wd) + 16384 + wq * 1024);                          \
    gl16(ws_ + 327680,  (wd) + 20480 + wq * 1024);                          \
} while (0)

__global__ __launch_bounds__(256) void proj_qkv(const float* __restrict__ x,
                                                const __bf16* __restrict__ Wt,
                                                const float* __restrict__ bk,
                                                const float* __restrict__ bq,
                                                const float* __restrict__ bv,
                                                __bf16* __restrict__ Kg,
                                                __bf16* __restrict__ Qg,
                                                __bf16* __restrict__ Vt) {
    // x tile: [32 rows][64 f32] = 8KB, phys byte = r*256 + ((c16)^(r&7))*16
    // W tile: [192 rows][64 bf16] = 24KB, phys byte = n*128 + ((c16)^(n&7))*16
    __shared__ char smem[65536];

    int tid  = threadIdx.x;
    int wq   = tid >> 6;
    int lane = tid & 63;
    int lo = lane & 15, g = lane >> 4;
    int swz = lo & 7;
    int w2 = wq >> 1, wc = wq & 1;
    int r0 = w2 * 16, n0 = wc * 96;
    int row0 = blockIdx.x * 32;

    // pre-swizzled global sources (chunk c = p ^ (row&7); LDS dest linear)
    const char* xsrc = (const char*)(x + (size_t)(row0 + (tid >> 4)) * C_
                                       + (size_t)(((tid & 15) ^ ((tid >> 4) & 7)) * 4));
    const char* wsrc = (const char*)Wt + (size_t)(tid >> 3) * 2048
                                       + (size_t)(((tid & 7) ^ ((tid >> 3) & 7)) * 16);

    char* xcur = smem;          char* xnxt = smem + 8192;
    char* wcur = smem + 16384;  char* wnxt = smem + 40960;

    f32x4 acc[6];
#pragma unroll
    for (int nt = 0; nt < 6; ++nt) acc[nt] = (f32x4){0.f, 0.f, 0.f, 0.f};

    STAGE(xcur, wcur, 0);
    __syncthreads();

#pragma unroll 1
    for (int step = 0; step < 16; ++step) {
        if (step < 15) STAGE(xnxt, wnxt, (step + 1) * 64);

        // A fragments (f32 -> bf16): lane holds x[r0+lo][kc*32 + g*8 + j]
        bf16x8 af[2];
        const char* ap = xcur + (r0 + lo) * 256;
#pragma unroll
        for (int kc = 0; kc < 2; ++kc) {
            int ch0 = kc * 8 + g * 2;
            f32x4 a0 = *(const f32x4*)(ap + ((ch0)     ^ swz) * 16);
            f32x4 a1 = *(const f32x4*)(ap + ((ch0 + 1) ^ swz) * 16);
            bf16x8 t;
            t[0] = (__bf16)a0[0]; t[1] = (__bf16)a0[1];
            t[2] = (__bf16)a0[2]; t[3] = (__bf16)a0[3];
            t[4] = (__bf16)a1[0]; t[5] = (__bf16)a1[1];
            t[6] = (__bf16)a1[2]; t[7] = (__bf16)a1[3];
            af[kc] = t;
        }
        // B fragments + MFMA: B[n0+nt*16+lo][kc*32 + g*8 + j]
#pragma unroll
        for (int nt = 0; nt < 6; ++nt) {
            const char* bp_ = wcur + (n0 + nt * 16 + lo) * 128;
#pragma unroll
            for (int kc = 0; kc < 2; ++kc) {
                bf16x8 bf_ = *(const bf16x8*)(bp_ + ((kc * 4 + g) ^ swz) * 16);
                acc[nt] = MFMA16(af[kc], bf_, acc[nt]);
            }
        }
        __syncthreads();
        char* t1 = xcur; xcur = xnxt; xnxt = t1;
        char* t2 = wcur; wcur = wnxt; wnxt = t2;
    }

    // epilogue. D: row = r0 + 4g + r (x row), col = n0 + nt*16 + lo.
    int b_   = row0 >> 12;
    int tloc = row0 & (T_ - 1);
#pragma unroll
    for (int nt = 0; nt < 6; ++nt) {
        int col = n0 + nt * 16 + lo;
        int mat = col >> 6, h = col & 63;
        const float* bp = (mat == 0) ? bk : ((mat == 1) ? bq : bv);
        float bb = bp[h];
        if (mat == 2) {                            // V -> transposed [B][64][T]
            bf16x4 pv;
#pragma unroll
            for (int r = 0; r < 4; ++r) pv[r] = (__bf16)(acc[nt][r] + bb);
            *(bf16x4*)(Vt + (size_t)(b_ * 64 + h) * T_ + tloc + r0 + 4 * g) = pv;
        } else if (mat == 1) {
#pragma unroll
            for (int r = 0; r < 4; ++r)
                Qg[(size_t)(row0 + r0 + 4 * g + r) * H_ + h] = (__bf16)((acc[nt][r] + bb) * QSCALE);
        } else {
#pragma unroll
            for (int r = 0; r < 4; ++r)
                Kg[(size_t)(row0 + r0 + 4 * g + r) * H_ + h] = (__bf16)(acc[nt][r] + bb);
        }
    }
}

// ---------------------------------------------------------------------------
// attn: flash attention, 8 waves/block, in-block split-k (R2 structure:
// 32 waves/CU, no inner barriers, direct-L2 K/V).
// Swapped QK^T: St[k][q] = mfma(K, Q) so softmax rows are lane-local.
// ---------------------------------------------------------------------------
__global__ __launch_bounds__(512) void attn_fwd(const __bf16* __restrict__ Qg,
                                                const __bf16* __restrict__ Kg,
                                                const __bf16* __restrict__ Vt,
                                                float* __restrict__ out) {
    // 8 x 4KB regions: per-wave P-relayout buffer during the loop (first 2KB),
    // then the wave's 16x64 f32 acc partial. + ml[8][16][2].
    __shared__ alignas(16) char smem[8 * 4096 + 8 * 16 * 2 * 4];

    int tid  = threadIdx.x;
    int w    = tid >> 6;
    int lane = tid & 63;
    int lo = lane & 15, g = lane >> 4;

    int bid = blockIdx.x;
    int b   = bid >> 8;
    int qt  = 255 - (bid & 255);                   // heavy tiles launch first
    int q0  = qt * 16;

    char* pl = smem + w * 4096;                    // wave-private P buffer

    // Q as B-fragment: lane holds Q[q0+lo][c*32 + g*8 + j]  (already *QSCALE)
    const __bf16* qp = Qg + (size_t)(b * T_ + q0 + lo) * H_ + g * 8;
    bf16x8 qb0 = *(const bf16x8*)(qp);
    bf16x8 qb1 = *(const bf16x8*)(qp + 32);

    f32x4 acc[4];
#pragma unroll
    for (int ht = 0; ht < 4; ++ht) acc[ht] = (f32x4){0.f, 0.f, 0.f, 0.f};
    float m = -1e30f, l = 0.f;

    int niter = (q0 >> 6) + 1;                     // only last k-block is partial
    for (int kb = w; kb < niter; kb += 8) {
        int k0 = kb << 6;
        f32x4 st[4];
#pragma unroll
        for (int kt = 0; kt < 4; ++kt) {
            const __bf16* kp = Kg + (size_t)(b * T_ + k0 + kt * 16 + lo) * H_ + g * 8;
            bf16x8 ka0 = *(const bf16x8*)(kp);
            bf16x8 ka1 = *(const bf16x8*)(kp + 32);
            f32x4 z = (f32x4){0.f, 0.f, 0.f, 0.f};
            z = MFMA16(ka0, qb0, z);               // St[k][q]: col=q=lo, row=k=4g+r
            z = MFMA16(ka1, qb1, z);
            st[kt] = z;
        }
        if (kb == niter - 1) {                     // causal mask (partial tile)
#pragma unroll
            for (int kt = 0; kt < 4; ++kt)
#pragma unroll
                for (int r = 0; r < 4; ++r) {
                    int kabs = k0 + kt * 16 + 4 * g + r;
                    if (kabs > q0 + lo) st[kt][r] = -1e30f;
                }
        }
        // online softmax (exp2 domain)
        float mloc = -1e30f;
#pragma unroll
        for (int kt = 0; kt < 4; ++kt)
#pragma unroll
            for (int r = 0; r < 4; ++r) mloc = fmaxf(mloc, st[kt][r]);
        mloc = fmaxf(mloc, __shfl_xor(mloc, 16));
        mloc = fmaxf(mloc, __shfl_xor(mloc, 32));
        float mnew  = fmaxf(m, mloc);
        float alpha = exp2f(m - mnew);
        float ls = 0.f;
#pragma unroll
        for (int kt = 0; kt < 4; ++kt)
#pragma unroll
            for (int r = 0; r < 4; ++r) {
                float pe = exp2f(st[kt][r] - mnew);
                st[kt][r] = pe;
                ls += pe;
            }
        ls += __shfl_xor(ls, 16);
        ls += __shfl_xor(ls, 32);
        l = l * alpha + ls;
        m = mnew;
        // rescale acc: acc rows are q = 4g+r; alpha lives at lanes with lo == q
#pragma unroll
        for (int r = 0; r < 4; ++r) {
            float ar = __shfl(alpha, 4 * g + r);
#pragma unroll
            for (int ht = 0; ht < 4; ++ht) acc[ht][r] *= ar;
        }
        // P -> LDS (bf16, XOR swizzle: 2-way max)
#pragma unroll
        for (int kt = 0; kt < 4; ++kt) {
            bf16x4 pk;
#pragma unroll
            for (int r = 0; r < 4; ++r) pk[r] = (__bf16)st[kt][r];
            int waddr = (lo * 128 + kt * 32 + g * 8) ^ ((lo & 7) << 4);
            *(bf16x4*)(pl + waddr) = pk;
        }
        // PV: A = P[q][k], B = V^T rows (16B/lane contiguous)
#pragma unroll
        for (int c = 0; c < 2; ++c) {
            int raddr = (lo * 128 + c * 64 + g * 16) ^ ((lo & 7) << 4);
            bf16x8 pa = *(const bf16x8*)(pl + raddr);
#pragma unroll
            for (int ht = 0; ht < 4; ++ht) {
                bf16x8 vb = *(const bf16x8*)(Vt + (size_t)(b * 64 + ht * 16 + lo) * T_ + k0 + c * 32 + g * 8);
                acc[ht] = MFMA16(pa, vb, acc[ht]);
            }
        }
    }

    // ---- write per-wave partials (reuses the P region; wave-private) ----
    float* ab = (float*)(smem + w * 4096);         // [16][64]
#pragma unroll
    for (int ht = 0; ht < 4; ++ht)
#pragma unroll
        for (int r = 0; r < 4; ++r)
            ab[(4 * g + r) * 64 + ht * 16 + lo] = acc[ht][r];
    float* ml = (float*)(smem + 8 * 4096);         // [8][16][2]
    if (g == 0) {
        ml[(w * 16 + lo) * 2 + 0] = m;
        ml[(w * 16 + lo) * 2 + 1] = l;
    }
    __syncthreads();

    // ---- merge 8 partials: 1024 outputs, 512 threads -> 2 each ----
    const float* fl = (const float*)smem;
#pragma unroll
    for (int i = 0; i < 2; ++i) {
        int e = i * 512 + tid;
        int q = e >> 6, h = e & 63;
        float M = -1e30f;
#pragma unroll
        for (int ww = 0; ww < 8; ++ww) M = fmaxf(M, ml[(ww * 16 + q) * 2]);
        float L = 0.f, O = 0.f;
#pragma unroll
        for (int ww = 0; ww < 8; ++ww) {
            float sc = exp2f(ml[(ww * 16 + q) * 2] - M);
            L += ml[(ww * 16 + q) * 2 + 1] * sc;
            O += fl[ww * 1024 + q * 64 + h] * sc;
        }
        out[(size_t)(b * T_ + q0 + q) * H_ + h] = O / L;
    }
}

// ---------------------------------------------------------------------------
extern "C" void kernel_launch(void* const* d_in, const int* in_sizes, int n_in,
                              void* d_out, int out_size, void* d_ws, size_t ws_size,
                              hipStream_t stream) {
    const float* x  = (const float*)d_in[0];
    const float* Wk = (const float*)d_in[1];
    const float* bk = (const float*)d_in[2];
    const float* Wq = (const float*)d_in[3];
    const float* bq = (const float*)d_in[4];
    const float* Wv = (const float*)d_in[5];
    const float* bv = (const float*)d_in[6];

    char* ws = (char*)d_ws;
    // ws layout: Wt 384KB | Kg 2MB | Qg 2MB | Vt 2MB
    __bf16* Wt = (__bf16*)(ws);
    __bf16* Kg = (__bf16*)(ws + 393216);
    __bf16* Qg = (__bf16*)(ws + 393216 + 2097152);
    __bf16* Vt = (__bf16*)(ws + 393216 + 2 * 2097152);
    float* out = (float*)d_out;

    prep_wt<<<192, 256, 0, stream>>>(Wk, Wq, Wv, Wt);
    proj_qkv<<<512, 256, 0, stream>>>(x, Wt, bk, bq, bv, Kg, Qg, Vt);
    attn_fwd<<<B_ * (T_ / 16), 512, 0, stream>>>(Qg, Kg, Vt, out);
}

// Round 6
// 93.955 us; speedup vs baseline: 1.5779x; 1.2579x over previous
//
#include <hip/hip_runtime.h>

// Head: B=4, T=4096, C=1024, H=64. out = softmax(causal((x@Wq+bq)@(x@Wk+bk)^T * C^-0.5)) @ (x@Wv+bv)
#define B_ 4
#define T_ 4096
#define C_ 1024
#define H_ 64
// C^-0.5 * log2(e): folds softmax scale into Q, moves softmax into exp2 domain.
#define QSCALE 0.045084220027780106f

typedef float  f32x4  __attribute__((ext_vector_type(4)));
typedef __bf16 bf16x8 __attribute__((ext_vector_type(8)));
typedef __bf16 bf16x4 __attribute__((ext_vector_type(4)));

#define MFMA16(a, b, c) __builtin_amdgcn_mfma_f32_16x16x32_bf16((a), (b), (c), 0, 0, 0)

// async global->LDS, 16B per lane; LDS dest is wave-uniform base + lane*16.
__device__ __forceinline__ void gl16(const void* g, void* l) {
    __builtin_amdgcn_global_load_lds(
        (const __attribute__((address_space(1))) void*)g,
        (__attribute__((address_space(3))) void*)l, 16, 0, 0);
}

// ---------------------------------------------------------------------------
// prep: Wt[mat][n][k] = W_mat[k][n] as bf16 (LDS tile transpose). 192 blocks.
// ---------------------------------------------------------------------------
__global__ __launch_bounds__(256) void prep_wt(const float* __restrict__ Wk,
                                               const float* __restrict__ Wq,
                                               const float* __restrict__ Wv,
                                               __bf16* __restrict__ Wt) {
    __shared__ float tile[16][65];
    int tid = threadIdx.x;
    int mat = blockIdx.x >> 6;
    int k0  = (blockIdx.x & 63) * 16;
    const float* W = (mat == 0) ? Wk : ((mat == 1) ? Wq : Wv);
#pragma unroll
    for (int i = 0; i < 4; ++i) {
        int e = i * 256 + tid;
        int ki = e >> 6, n = e & 63;
        tile[ki][n] = W[(size_t)(k0 + ki) * 64 + n];
    }
    __syncthreads();
#pragma unroll
    for (int i = 0; i < 4; ++i) {
        int e = i * 256 + tid;
        int n = e >> 4, kj = e & 15;
        Wt[(size_t)mat * 65536 + (size_t)n * 1024 + k0 + kj] = (__bf16)tile[kj][n];
    }
}

// ---------------------------------------------------------------------------
// proj: m97-style LDS-staged GEMM. M=16384, N=192 (K|Q|V), K=1024.
// 512 blocks x 4 waves. BM=32, BN=192, BK=64. Double-buffered LDS staged via
// global_load_lds (linear dest, XOR-preswizzled global source; matching XOR
// on ds_read -> conflict-free). One barrier per K-step.
// ---------------------------------------------------------------------------
#define STAGE(xd, wd, kk) do {                                              \
    const char* xs_ = xsrc + (size_t)(kk) * 4;                              \
    gl16(xs_,          (xd) + wq * 1024);                                   \
    gl16(xs_ + 65536,  (xd) + 4096 + wq * 1024);                            \
    const char* ws_ = wsrc + (size_t)(kk) * 2;                              \
    gl16(ws_,           (wd) + wq * 1024);                                  \
    gl16(ws_ + 65536,   (wd) + 4096  + wq * 1024);                          \
    gl16(ws_ + 131072,  (wd) + 8192  + wq * 1024);                          \
    gl16(ws_ + 196608,  (wd) + 12288 + wq * 1024);                          \
    gl16(ws_ + 262144,  (wd) + 16384 + wq * 1024);                          \
    gl16(ws_ + 327680,  (wd) + 20480 + wq * 1024);                          \
} while (0)

__global__ __launch_bounds__(256) void proj_qkv(const float* __restrict__ x,
                                                const __bf16* __restrict__ Wt,
                                                const float* __restrict__ bk,
                                                const float* __restrict__ bq,
                                                const float* __restrict__ bv,
                                                __bf16* __restrict__ Kg,
                                                __bf16* __restrict__ Qg,
                                                __bf16* __restrict__ Vt) {
    // x tile: [32 rows][64 f32] = 8KB, phys byte = r*256 + ((c16)^(r&7))*16
    // W tile: [192 rows][64 bf16] = 24KB, phys byte = n*128 + ((c16)^(n&7))*16
    __shared__ char smem[65536];

    int tid  = threadIdx.x;
    int wq   = tid >> 6;
    int lane = tid & 63;
    int lo = lane & 15, g = lane >> 4;
    int swz = lo & 7;
    int w2 = wq >> 1, wc = wq & 1;
    int r0 = w2 * 16, n0 = wc * 96;
    int row0 = blockIdx.x * 32;

    // pre-swizzled global sources (chunk c = p ^ (row&7); LDS dest linear)
    const char* xsrc = (const char*)(x + (size_t)(row0 + (tid >> 4)) * C_
                                       + (size_t)(((tid & 15) ^ ((tid >> 4) & 7)) * 4));
    const char* wsrc = (const char*)Wt + (size_t)(tid >> 3) * 2048
                                       + (size_t)(((tid & 7) ^ ((tid >> 3) & 7)) * 16);

    char* xcur = smem;          char* xnxt = smem + 8192;
    char* wcur = smem + 16384;  char* wnxt = smem + 40960;

    f32x4 acc[6];
#pragma unroll
    for (int nt = 0; nt < 6; ++nt) acc[nt] = (f32x4){0.f, 0.f, 0.f, 0.f};

    STAGE(xcur, wcur, 0);
    __syncthreads();

#pragma unroll 1
    for (int step = 0; step < 16; ++step) {
        if (step < 15) STAGE(xnxt, wnxt, (step + 1) * 64);

        // A fragments (f32 -> bf16): lane holds x[r0+lo][kc*32 + g*8 + j]
        bf16x8 af[2];
        const char* ap = xcur + (r0 + lo) * 256;
#pragma unroll
        for (int kc = 0; kc < 2; ++kc) {
            int ch0 = kc * 8 + g * 2;
            f32x4 a0 = *(const f32x4*)(ap + ((ch0)     ^ swz) * 16);
            f32x4 a1 = *(const f32x4*)(ap + ((ch0 + 1) ^ swz) * 16);
            bf16x8 t;
            t[0] = (__bf16)a0[0]; t[1] = (__bf16)a0[1];
            t[2] = (__bf16)a0[2]; t[3] = (__bf16)a0[3];
            t[4] = (__bf16)a1[0]; t[5] = (__bf16)a1[1];
            t[6] = (__bf16)a1[2]; t[7] = (__bf16)a1[3];
            af[kc] = t;
        }
        // B fragments + MFMA: B[n0+nt*16+lo][kc*32 + g*8 + j]
#pragma unroll
        for (int nt = 0; nt < 6; ++nt) {
            const char* bp_ = wcur + (n0 + nt * 16 + lo) * 128;
#pragma unroll
            for (int kc = 0; kc < 2; ++kc) {
                bf16x8 bf_ = *(const bf16x8*)(bp_ + ((kc * 4 + g) ^ swz) * 16);
                acc[nt] = MFMA16(af[kc], bf_, acc[nt]);
            }
        }
        __syncthreads();
        char* t1 = xcur; xcur = xnxt; xnxt = t1;
        char* t2 = wcur; wcur = wnxt; wnxt = t2;
    }

    // epilogue. D: row = r0 + 4g + r (x row), col = n0 + nt*16 + lo.
    int b_   = row0 >> 12;
    int tloc = row0 & (T_ - 1);
#pragma unroll
    for (int nt = 0; nt < 6; ++nt) {
        int col = n0 + nt * 16 + lo;
        int mat = col >> 6, h = col & 63;
        const float* bp = (mat == 0) ? bk : ((mat == 1) ? bq : bv);
        float bb = bp[h];
        if (mat == 2) {                            // V -> transposed [B][64][T]
            bf16x4 pv;
#pragma unroll
            for (int r = 0; r < 4; ++r) pv[r] = (__bf16)(acc[nt][r] + bb);
            *(bf16x4*)(Vt + (size_t)(b_ * 64 + h) * T_ + tloc + r0 + 4 * g) = pv;
        } else if (mat == 1) {
#pragma unroll
            for (int r = 0; r < 4; ++r)
                Qg[(size_t)(row0 + r0 + 4 * g + r) * H_ + h] = (__bf16)((acc[nt][r] + bb) * QSCALE);
        } else {
#pragma unroll
            for (int r = 0; r < 4; ++r)
                Kg[(size_t)(row0 + r0 + 4 * g + r) * H_ + h] = (__bf16)(acc[nt][r] + bb);
        }
    }
}

// ---------------------------------------------------------------------------
// attn: flash attention, 8 waves/block, in-block split-k, direct-L2 K/V,
// 32 waves/CU.  Per-CU balance: blocks at stride 256 share a CU (measured via
// R2-vs-R5 natural experiment), so map j=bid>>2 through a quadrant-complement
// bijection -> the 4 co-resident blocks' qt sum to a constant (510).
// Swapped QK^T: St[k][q] = mfma(K, Q) so softmax rows are lane-local.
// ---------------------------------------------------------------------------
__global__ __launch_bounds__(512) void attn_fwd(const __bf16* __restrict__ Qg,
                                                const __bf16* __restrict__ Kg,
                                                const __bf16* __restrict__ Vt,
                                                float* __restrict__ out) {
    // 8 x 4KB regions: per-wave P-relayout buffer during the loop (first 2KB),
    // then the wave's 16x64 f32 acc partial. + ml[8][16][2].
    __shared__ alignas(16) char smem[8 * 4096 + 8 * 16 * 2 * 4];

    int tid  = threadIdx.x;
    int w    = tid >> 6;
    int lane = tid & 63;
    int lo = lane & 15, g = lane >> 4;

    int bid = blockIdx.x;
    int b   = bid & 3;
    int j   = bid >> 2;
    int quad = j >> 6, r_ = j & 63;
    int qt  = (quad << 6) | ((quad & 1) ? (63 - r_) : r_);   // CU-balanced
    int q0  = qt * 16;

    char* pl = smem + w * 4096;                    // wave-private P buffer

    // Q as B-fragment: lane holds Q[q0+lo][c*32 + g*8 + j]  (already *QSCALE)
    const __bf16* qp = Qg + (size_t)(b * T_ + q0 + lo) * H_ + g * 8;
    bf16x8 qb0 = *(const bf16x8*)(qp);
    bf16x8 qb1 = *(const bf16x8*)(qp + 32);

    f32x4 acc[4];
#pragma unroll
    for (int ht = 0; ht < 4; ++ht) acc[ht] = (f32x4){0.f, 0.f, 0.f, 0.f};
    float m = -1e30f, l = 0.f;

    int niter = (q0 >> 6) + 1;                     // only last k-block is partial
    for (int kb = w; kb < niter; kb += 8) {
        int k0 = kb << 6;
        f32x4 st[4];
#pragma unroll
        for (int kt = 0; kt < 4; ++kt) {
            const __bf16* kp = Kg + (size_t)(b * T_ + k0 + kt * 16 + lo) * H_ + g * 8;
            bf16x8 ka0 = *(const bf16x8*)(kp);
            bf16x8 ka1 = *(const bf16x8*)(kp + 32);
            f32x4 z = (f32x4){0.f, 0.f, 0.f, 0.f};
            __builtin_amdgcn_s_setprio(1);
            z = MFMA16(ka0, qb0, z);               // St[k][q]: col=q=lo, row=k=4g+r
            z = MFMA16(ka1, qb1, z);
            __builtin_amdgcn_s_setprio(0);
            st[kt] = z;
        }
        if (kb == niter - 1) {                     // causal mask (partial tile)
#pragma unroll
            for (int kt = 0; kt < 4; ++kt)
#pragma unroll
                for (int r = 0; r < 4; ++r) {
                    int kabs = k0 + kt * 16 + 4 * g + r;
                    if (kabs > q0 + lo) st[kt][r] = -1e30f;
                }
        }
        // online softmax (exp2 domain)
        float mloc = -1e30f;
#pragma unroll
        for (int kt = 0; kt < 4; ++kt)
#pragma unroll
            for (int r = 0; r < 4; ++r) mloc = fmaxf(mloc, st[kt][r]);
        mloc = fmaxf(mloc, __shfl_xor(mloc, 16));
        mloc = fmaxf(mloc, __shfl_xor(mloc, 32));
        float mnew  = fmaxf(m, mloc);
        float alpha = exp2f(m - mnew);
        float ls = 0.f;
#pragma unroll
        for (int kt = 0; kt < 4; ++kt)
#pragma unroll
            for (int r = 0; r < 4; ++r) {
                float pe = exp2f(st[kt][r] - mnew);
                st[kt][r] = pe;
                ls += pe;
            }
        ls += __shfl_xor(ls, 16);
        ls += __shfl_xor(ls, 32);
        l = l * alpha + ls;
        m = mnew;
        // rescale acc: acc rows are q = 4g+r; alpha lives at lanes with lo == q
#pragma unroll
        for (int r = 0; r < 4; ++r) {
            float ar = __shfl(alpha, 4 * g + r);
#pragma unroll
            for (int ht = 0; ht < 4; ++ht) acc[ht][r] *= ar;
        }
        // P -> LDS (bf16, XOR swizzle: 2-way max)
#pragma unroll
        for (int kt = 0; kt < 4; ++kt) {
            bf16x4 pk;
#pragma unroll
            for (int r = 0; r < 4; ++r) pk[r] = (__bf16)st[kt][r];
            int waddr = (lo * 128 + kt * 32 + g * 8) ^ ((lo & 7) << 4);
            *(bf16x4*)(pl + waddr) = pk;
        }
        // PV: A = P[q][k], B = V^T rows (16B/lane contiguous)
#pragma unroll
        for (int c = 0; c < 2; ++c) {
            int raddr = (lo * 128 + c * 64 + g * 16) ^ ((lo & 7) << 4);
            bf16x8 pa = *(const bf16x8*)(pl + raddr);
            __builtin_amdgcn_s_setprio(1);
#pragma unroll
            for (int ht = 0; ht < 4; ++ht) {
                bf16x8 vb = *(const bf16x8*)(Vt + (size_t)(b * 64 + ht * 16 + lo) * T_ + k0 + c * 32 + g * 8);
                acc[ht] = MFMA16(pa, vb, acc[ht]);
            }
            __builtin_amdgcn_s_setprio(0);
        }
    }

    // ---- write per-wave partials (reuses the P region; wave-private) ----
    float* ab = (float*)(smem + w * 4096);         // [16][64]
#pragma unroll
    for (int ht = 0; ht < 4; ++ht)
#pragma unroll
        for (int r = 0; r < 4; ++r)
            ab[(4 * g + r) * 64 + ht * 16 + lo] = acc[ht][r];
    float* ml = (float*)(smem + 8 * 4096);         // [8][16][2]
    if (g == 0) {
        ml[(w * 16 + lo) * 2 + 0] = m;
        ml[(w * 16 + lo) * 2 + 1] = l;
    }
    __syncthreads();

    // ---- merge 8 partials: 1024 outputs, 512 threads -> 2 each ----
    const float* fl = (const float*)smem;
#pragma unroll
    for (int i = 0; i < 2; ++i) {
        int e = i * 512 + tid;
        int q = e >> 6, h = e & 63;
        float M = -1e30f;
#pragma unroll
        for (int ww = 0; ww < 8; ++ww) M = fmaxf(M, ml[(ww * 16 + q) * 2]);
        float L = 0.f, O = 0.f;
#pragma unroll
        for (int ww = 0; ww < 8; ++ww) {
            float sc = exp2f(ml[(ww * 16 + q) * 2] - M);
            L += ml[(ww * 16 + q) * 2 + 1] * sc;
            O += fl[ww * 1024 + q * 64 + h] * sc;
        }
        out[(size_t)(b * T_ + q0 + q) * H_ + h] = O / L;
    }
}

// ---------------------------------------------------------------------------
extern "C" void kernel_launch(void* const* d_in, const int* in_sizes, int n_in,
                              void* d_out, int out_size, void* d_ws, size_t ws_size,
                              hipStream_t stream) {
    const float* x  = (const float*)d_in[0];
    const float* Wk = (const float*)d_in[1];
    const float* bk = (const float*)d_in[2];
    const float* Wq = (const float*)d_in[3];
    const float* bq = (const float*)d_in[4];
    const float* Wv = (const float*)d_in[5];
    const float* bv = (const float*)d_in[6];

    char* ws = (char*)d_ws;
    // ws layout: Wt 384KB | Kg 2MB | Qg 2MB | Vt 2MB
    __bf16* Wt = (__bf16*)(ws);
    __bf16* Kg = (__bf16*)(ws + 393216);
    __bf16* Qg = (__bf16*)(ws + 393216 + 2097152);
    __bf16* Vt = (__bf16*)(ws + 393216 + 2 * 2097152);
    float* out = (float*)d_out;

    prep_wt<<<192, 256, 0, stream>>>(Wk, Wq, Wv, Wt);
    proj_qkv<<<512, 256, 0, stream>>>(x, Wt, bk, bq, bv, Kg, Qg, Vt);
    attn_fwd<<<B_ * (T_ / 16), 512, 0, stream>>>(Qg, Kg, Vt, out);
}

// Round 7
// 91.532 us; speedup vs baseline: 1.6196x; 1.0265x over previous
//
#include <hip/hip_runtime.h>

// Head: B=4, T=4096, C=1024, H=64. out = softmax(causal((x@Wq+bq)@(x@Wk+bk)^T * C^-0.5)) @ (x@Wv+bv)
#define B_ 4
#define T_ 4096
#define C_ 1024
#define H_ 64
// C^-0.5 * log2(e): folds softmax scale into Q, moves softmax into exp2 domain.
#define QSCALE 0.045084220027780106f

typedef float  f32x4  __attribute__((ext_vector_type(4)));
typedef __bf16 bf16x8 __attribute__((ext_vector_type(8)));
typedef __bf16 bf16x4 __attribute__((ext_vector_type(4)));

#define MFMA16(a, b, c) __builtin_amdgcn_mfma_f32_16x16x32_bf16((a), (b), (c), 0, 0, 0)

// async global->LDS, 16B per lane; LDS dest is wave-uniform base + lane*16.
__device__ __forceinline__ void gl16(const void* g, void* l) {
    __builtin_amdgcn_global_load_lds(
        (const __attribute__((address_space(1))) void*)g,
        (__attribute__((address_space(3))) void*)l, 16, 0, 0);
}

// ---------------------------------------------------------------------------
// prep: Wt[mat][n][k] = W_mat[k][n] as bf16 (LDS tile transpose). 192 blocks.
// ---------------------------------------------------------------------------
__global__ __launch_bounds__(256) void prep_wt(const float* __restrict__ Wk,
                                               const float* __restrict__ Wq,
                                               const float* __restrict__ Wv,
                                               __bf16* __restrict__ Wt) {
    __shared__ float tile[16][65];
    int tid = threadIdx.x;
    int mat = blockIdx.x >> 6;
    int k0  = (blockIdx.x & 63) * 16;
    const float* W = (mat == 0) ? Wk : ((mat == 1) ? Wq : Wv);
#pragma unroll
    for (int i = 0; i < 4; ++i) {
        int e = i * 256 + tid;
        int ki = e >> 6, n = e & 63;
        tile[ki][n] = W[(size_t)(k0 + ki) * 64 + n];
    }
    __syncthreads();
#pragma unroll
    for (int i = 0; i < 4; ++i) {
        int e = i * 256 + tid;
        int n = e >> 4, kj = e & 15;
        Wt[(size_t)mat * 65536 + (size_t)n * 1024 + k0 + kj] = (__bf16)tile[kj][n];
    }
}

// ---------------------------------------------------------------------------
// proj: m97-style LDS-staged GEMM (R5/R6 version, measured ~18.5us).
// ---------------------------------------------------------------------------
#define STAGE(xd, wd, kk) do {                                              \
    const char* xs_ = xsrc + (size_t)(kk) * 4;                              \
    gl16(xs_,          (xd) + wq * 1024);                                   \
    gl16(xs_ + 65536,  (xd) + 4096 + wq * 1024);                            \
    const char* ws_ = wsrc + (size_t)(kk) * 2;                              \
    gl16(ws_,           (wd) + wq * 1024);                                  \
    gl16(ws_ + 65536,   (wd) + 4096  + wq * 1024);                          \
    gl16(ws_ + 131072,  (wd) + 8192  + wq * 1024);                          \
    gl16(ws_ + 196608,  (wd) + 12288 + wq * 1024);                          \
    gl16(ws_ + 262144,  (wd) + 16384 + wq * 1024);                          \
    gl16(ws_ + 327680,  (wd) + 20480 + wq * 1024);                          \
} while (0)

__global__ __launch_bounds__(256) void proj_qkv(const float* __restrict__ x,
                                                const __bf16* __restrict__ Wt,
                                                const float* __restrict__ bk,
                                                const float* __restrict__ bq,
                                                const float* __restrict__ bv,
                                                __bf16* __restrict__ Kg,
                                                __bf16* __restrict__ Qg,
                                                __bf16* __restrict__ Vt) {
    __shared__ char smem[65536];

    int tid  = threadIdx.x;
    int wq   = tid >> 6;
    int lane = tid & 63;
    int lo = lane & 15, g = lane >> 4;
    int swz = lo & 7;
    int w2 = wq >> 1, wc = wq & 1;
    int r0 = w2 * 16, n0 = wc * 96;
    int row0 = blockIdx.x * 32;

    const char* xsrc = (const char*)(x + (size_t)(row0 + (tid >> 4)) * C_
                                       + (size_t)(((tid & 15) ^ ((tid >> 4) & 7)) * 4));
    const char* wsrc = (const char*)Wt + (size_t)(tid >> 3) * 2048
                                       + (size_t)(((tid & 7) ^ ((tid >> 3) & 7)) * 16);

    char* xcur = smem;          char* xnxt = smem + 8192;
    char* wcur = smem + 16384;  char* wnxt = smem + 40960;

    f32x4 acc[6];
#pragma unroll
    for (int nt = 0; nt < 6; ++nt) acc[nt] = (f32x4){0.f, 0.f, 0.f, 0.f};

    STAGE(xcur, wcur, 0);
    __syncthreads();

#pragma unroll 1
    for (int step = 0; step < 16; ++step) {
        if (step < 15) STAGE(xnxt, wnxt, (step + 1) * 64);

        bf16x8 af[2];
        const char* ap = xcur + (r0 + lo) * 256;
#pragma unroll
        for (int kc = 0; kc < 2; ++kc) {
            int ch0 = kc * 8 + g * 2;
            f32x4 a0 = *(const f32x4*)(ap + ((ch0)     ^ swz) * 16);
            f32x4 a1 = *(const f32x4*)(ap + ((ch0 + 1) ^ swz) * 16);
            bf16x8 t;
            t[0] = (__bf16)a0[0]; t[1] = (__bf16)a0[1];
            t[2] = (__bf16)a0[2]; t[3] = (__bf16)a0[3];
            t[4] = (__bf16)a1[0]; t[5] = (__bf16)a1[1];
            t[6] = (__bf16)a1[2]; t[7] = (__bf16)a1[3];
            af[kc] = t;
        }
#pragma unroll
        for (int nt = 0; nt < 6; ++nt) {
            const char* bp_ = wcur + (n0 + nt * 16 + lo) * 128;
#pragma unroll
            for (int kc = 0; kc < 2; ++kc) {
                bf16x8 bf_ = *(const bf16x8*)(bp_ + ((kc * 4 + g) ^ swz) * 16);
                acc[nt] = MFMA16(af[kc], bf_, acc[nt]);
            }
        }
        __syncthreads();
        char* t1 = xcur; xcur = xnxt; xnxt = t1;
        char* t2 = wcur; wcur = wnxt; wnxt = t2;
    }

    int b_   = row0 >> 12;
    int tloc = row0 & (T_ - 1);
#pragma unroll
    for (int nt = 0; nt < 6; ++nt) {
        int col = n0 + nt * 16 + lo;
        int mat = col >> 6, h = col & 63;
        const float* bp = (mat == 0) ? bk : ((mat == 1) ? bq : bv);
        float bb = bp[h];
        if (mat == 2) {                            // V -> transposed [B][64][T]
            bf16x4 pv;
#pragma unroll
            for (int r = 0; r < 4; ++r) pv[r] = (__bf16)(acc[nt][r] + bb);
            *(bf16x4*)(Vt + (size_t)(b_ * 64 + h) * T_ + tloc + r0 + 4 * g) = pv;
        } else if (mat == 1) {
#pragma unroll
            for (int r = 0; r < 4; ++r)
                Qg[(size_t)(row0 + r0 + 4 * g + r) * H_ + h] = (__bf16)((acc[nt][r] + bb) * QSCALE);
        } else {
#pragma unroll
            for (int r = 0; r < 4; ++r)
                Kg[(size_t)(row0 + r0 + 4 * g + r) * H_ + h] = (__bf16)(acc[nt][r] + bb);
        }
    }
}

// ---------------------------------------------------------------------------
// attn: one iteration of the flash loop for one 16-row q-tile / one 64-k tile.
// Swapped QK^T: St[k][q] = mfma(K, Q) so softmax rows are lane-local.
// ---------------------------------------------------------------------------
__device__ __forceinline__ void attn_iter(const __bf16* __restrict__ kgB,
                                          const __bf16* __restrict__ vtB,
                                          int k0, int q0, bool domask,
                                          bf16x8 qb0, bf16x8 qb1,
                                          f32x4 (&acc)[4], float& m, float& l,
                                          char* pl, int lo, int g) {
    f32x4 st[4];
#pragma unroll
    for (int kt = 0; kt < 4; ++kt) {
        const __bf16* kp = kgB + (size_t)(k0 + kt * 16 + lo) * H_ + g * 8;
        bf16x8 ka0 = *(const bf16x8*)(kp);
        bf16x8 ka1 = *(const bf16x8*)(kp + 32);
        f32x4 z = (f32x4){0.f, 0.f, 0.f, 0.f};
        __builtin_amdgcn_s_setprio(1);
        z = MFMA16(ka0, qb0, z);                   // col=q=lo, row=k=4g+r
        z = MFMA16(ka1, qb1, z);
        __builtin_amdgcn_s_setprio(0);
        st[kt] = z;
    }
    if (domask) {
#pragma unroll
        for (int kt = 0; kt < 4; ++kt)
#pragma unroll
            for (int r = 0; r < 4; ++r) {
                int kabs = k0 + kt * 16 + 4 * g + r;
                if (kabs > q0 + lo) st[kt][r] = -1e30f;
            }
    }
    float mloc = -1e30f;
#pragma unroll
    for (int kt = 0; kt < 4; ++kt)
#pragma unroll
        for (int r = 0; r < 4; ++r) mloc = fmaxf(mloc, st[kt][r]);
    mloc = fmaxf(mloc, __shfl_xor(mloc, 16));
    mloc = fmaxf(mloc, __shfl_xor(mloc, 32));
    float mnew  = fmaxf(m, mloc);
    float alpha = exp2f(m - mnew);
    float ls = 0.f;
#pragma unroll
    for (int kt = 0; kt < 4; ++kt)
#pragma unroll
        for (int r = 0; r < 4; ++r) {
            float pe = exp2f(st[kt][r] - mnew);
            st[kt][r] = pe;
            ls += pe;
        }
    ls += __shfl_xor(ls, 16);
    ls += __shfl_xor(ls, 32);
    l = l * alpha + ls;
    m = mnew;
#pragma unroll
    for (int r = 0; r < 4; ++r) {
        float ar = __shfl(alpha, 4 * g + r);
#pragma unroll
        for (int ht = 0; ht < 4; ++ht) acc[ht][r] *= ar;
    }
#pragma unroll
    for (int kt = 0; kt < 4; ++kt) {
        bf16x4 pk;
#pragma unroll
        for (int r = 0; r < 4; ++r) pk[r] = (__bf16)st[kt][r];
        int waddr = (lo * 128 + kt * 32 + g * 8) ^ ((lo & 7) << 4);
        *(bf16x4*)(pl + waddr) = pk;
    }
#pragma unroll
    for (int c = 0; c < 2; ++c) {
        int raddr = (lo * 128 + c * 64 + g * 16) ^ ((lo & 7) << 4);
        bf16x8 pa = *(const bf16x8*)(pl + raddr);
        __builtin_amdgcn_s_setprio(1);
#pragma unroll
        for (int ht = 0; ht < 4; ++ht) {
            bf16x8 vb = *(const bf16x8*)(vtB + (size_t)(ht * 16 + lo) * T_ + k0 + c * 32 + g * 8);
            acc[ht] = MFMA16(pa, vb, acc[ht]);
        }
        __builtin_amdgcn_s_setprio(0);
    }
}

// ---------------------------------------------------------------------------
// attn: 512 blocks x 8 waves. Block = complementary q-tile pair (i, 255-i):
// niter(i) + niter(255-i) == 65 for ALL i -> every wave in the grid does 8-9
// identical iterations (flat occupancy, no tail). Wave-uniform tile select,
// duplicated register state (static indexing). Two-pass LDS LSE merge.
// ---------------------------------------------------------------------------
__global__ __launch_bounds__(512) void attn_fwd(const __bf16* __restrict__ Qg,
                                                const __bf16* __restrict__ Kg,
                                                const __bf16* __restrict__ Vt,
                                                float* __restrict__ out) {
    // loop: P buffers 8 waves x 2KB = [0,16KB). merge: partials 8 x 4KB =
    // [0,32KB) + ml at 32KB (barrier-separated reuse).
    __shared__ alignas(16) char smem[32768 + 1024];

    int tid  = threadIdx.x;
    int w    = tid >> 6;
    int lane = tid & 63;
    int lo = lane & 15, g = lane >> 4;

    int bid = blockIdx.x;
    int b   = bid & 3;
    int i   = bid >> 2;                            // 0..127
    int q0A = i * 16;                              // low tile
    int q0B = (255 - i) * 16;                      // complement tile
    int nA  = (q0A >> 6) + 1;
    int nB  = (q0B >> 6) + 1;
    int ntot = nA + nB;                            // == 65 for all i

    const __bf16* kgB = Kg + (size_t)b * T_ * H_;
    const __bf16* vtB = Vt + (size_t)b * 64 * T_;

    char* pl = smem + w * 2048;                    // wave-private P buffer

    // Q fragments for both tiles (already *QSCALE)
    const __bf16* qpA = Qg + (size_t)(b * T_ + q0A + lo) * H_ + g * 8;
    bf16x8 qA0 = *(const bf16x8*)(qpA);
    bf16x8 qA1 = *(const bf16x8*)(qpA + 32);
    const __bf16* qpB = Qg + (size_t)(b * T_ + q0B + lo) * H_ + g * 8;
    bf16x8 qB0 = *(const bf16x8*)(qpB);
    bf16x8 qB1 = *(const bf16x8*)(qpB + 32);

    f32x4 accA[4], accB[4];
#pragma unroll
    for (int ht = 0; ht < 4; ++ht) {
        accA[ht] = (f32x4){0.f, 0.f, 0.f, 0.f};
        accB[ht] = (f32x4){0.f, 0.f, 0.f, 0.f};
    }
    float mA = -1e30f, lA = 0.f, mB = -1e30f, lB = 0.f;

    for (int idx = w; idx < ntot; idx += 8) {      // wave-uniform branch
        if (idx < nA) {
            attn_iter(kgB, vtB, idx << 6, q0A, idx == nA - 1,
                      qA0, qA1, accA, mA, lA, pl, lo, g);
        } else {
            int kb = idx - nA;
            attn_iter(kgB, vtB, kb << 6, q0B, kb == nB - 1,
                      qB0, qB1, accB, mB, lB, pl, lo, g);
        }
    }

    float* ml = (float*)(smem + 32768);            // [8][16][2]

    // ---- pass A: merge tile-A partials ----
    __syncthreads();                               // all waves done with P bufs
    {
        float* ab = (float*)(smem + w * 4096);     // [16][64]
#pragma unroll
        for (int ht = 0; ht < 4; ++ht)
#pragma unroll
            for (int r = 0; r < 4; ++r)
                ab[(4 * g + r) * 64 + ht * 16 + lo] = accA[ht][r];
        if (g == 0) {
            ml[(w * 16 + lo) * 2 + 0] = mA;
            ml[(w * 16 + lo) * 2 + 1] = lA;
        }
    }
    __syncthreads();
    {
        const float* fl = (const float*)smem;
#pragma unroll
        for (int jj = 0; jj < 2; ++jj) {
            int e = jj * 512 + tid;
            int q = e >> 6, h = e & 63;
            float M = -1e30f;
#pragma unroll
            for (int ww = 0; ww < 8; ++ww) M = fmaxf(M, ml[(ww * 16 + q) * 2]);
            float L = 0.f, O = 0.f;
#pragma unroll
            for (int ww = 0; ww < 8; ++ww) {
                float sc = exp2f(ml[(ww * 16 + q) * 2] - M);
                L += ml[(ww * 16 + q) * 2 + 1] * sc;
                O += fl[ww * 1024 + q * 64 + h] * sc;
            }
            out[(size_t)(b * T_ + q0A + q) * H_ + h] = O / L;
        }
    }

    // ---- pass B: merge tile-B partials ----
    __syncthreads();
    {
        float* ab = (float*)(smem + w * 4096);
#pragma unroll
        for (int ht = 0; ht < 4; ++ht)
#pragma unroll
            for (int r = 0; r < 4; ++r)
                ab[(4 * g + r) * 64 + ht * 16 + lo] = accB[ht][r];
        if (g == 0) {
            ml[(w * 16 + lo) * 2 + 0] = mB;
            ml[(w * 16 + lo) * 2 + 1] = lB;
        }
    }
    __syncthreads();
    {
        const float* fl = (const float*)smem;
#pragma unroll
        for (int jj = 0; jj < 2; ++jj) {
            int e = jj * 512 + tid;
            int q = e >> 6, h = e & 63;
            float M = -1e30f;
#pragma unroll
            for (int ww = 0; ww < 8; ++ww) M = fmaxf(M, ml[(ww * 16 + q) * 2]);
            float L = 0.f, O = 0.f;
#pragma unroll
            for (int ww = 0; ww < 8; ++ww) {
                float sc = exp2f(ml[(ww * 16 + q) * 2] - M);
                L += ml[(ww * 16 + q) * 2 + 1] * sc;
                O += fl[ww * 1024 + q * 64 + h] * sc;
            }
            out[(size_t)(b * T_ + q0B + q) * H_ + h] = O / L;
        }
    }
}

// ---------------------------------------------------------------------------
extern "C" void kernel_launch(void* const* d_in, const int* in_sizes, int n_in,
                              void* d_out, int out_size, void* d_ws, size_t ws_size,
                              hipStream_t stream) {
    const float* x  = (const float*)d_in[0];
    const float* Wk = (const float*)d_in[1];
    const float* bk = (const float*)d_in[2];
    const float* Wq = (const float*)d_in[3];
    const float* bq = (const float*)d_in[4];
    const float* Wv = (const float*)d_in[5];
    const float* bv = (const float*)d_in[6];

    char* ws = (char*)d_ws;
    // ws layout: Wt 384KB | Kg 2MB | Qg 2MB | Vt 2MB
    __bf16* Wt = (__bf16*)(ws);
    __bf16* Kg = (__bf16*)(ws + 393216);
    __bf16* Qg = (__bf16*)(ws + 393216 + 2097152);
    __bf16* Vt = (__bf16*)(ws + 393216 + 2 * 2097152);
    float* out = (float*)d_out;

    prep_wt<<<192, 256, 0, stream>>>(Wk, Wq, Wv, Wt);
    proj_qkv<<<512, 256, 0, stream>>>(x, Wt, bk, bq, bv, Kg, Qg, Vt);
    attn_fwd<<<512, 512, 0, stream>>>(Qg, Kg, Vt, out);
}